// Round 9
// baseline (314.290 us; speedup 1.0000x reference)
//
#include <hip/hip_runtime.h>
#include <stdint.h>
#include <math.h>

#define ROWLEN 84
#define F4PR 21              // float4s per row (84 floats)
#define RPB 256              // rows per tile (proven r6 config)
#define F4PT (RPB * F4PR)    // 5376 float4s per tile
#define CANDCAP (1u << 21)   // candidate cap (>= n, cannot overflow)

__device__ __forceinline__ uint32_t map_f(float f) {
    uint32_t u = __float_as_uint(f);
    return (u & 0x80000000u) ? ~u : (u | 0x80000000u);
}
__device__ __forceinline__ float unmap_f(uint32_t u) {
    uint32_t b = (u & 0x80000000u) ? (u & 0x7FFFFFFFu) : ~u;
    return __uint_as_float(b);
}

// Parallel bin find over hist[nbins] (global or LDS): bin b with
// suffix(b+1..) < target <= suffix(b..). 256 threads; identical result to all.
__device__ void find_parallel(const uint32_t* hist, int nbins, uint32_t target,
                              uint32_t* s, uint32_t* sc2, uint32_t* outBin, uint32_t* outAbove) {
    int tid = threadIdx.x;
    int chunks = nbins / 256;
    int base = tid * chunks;
    uint32_t part = 0;
    for (int i = 0; i < chunks; ++i) part += hist[base + i];
    s[tid] = part;
    __syncthreads();
    for (int off = 1; off < 256; off <<= 1) {  // suffix sums
        uint32_t v = (tid + off < 256) ? s[tid + off] : 0u;
        __syncthreads();
        s[tid] += v;
        __syncthreads();
    }
    uint32_t above_next = (tid < 255) ? s[tid + 1] : 0u;
    bool mine = (s[tid] >= target) && (above_next < target);  // exactly one thread
    if (mine) { sc2[0] = (uint32_t)tid; sc2[1] = above_next; }
    __syncthreads();
    uint32_t c = sc2[0], above = sc2[1];
    if (tid == 0) {  // <= chunks serial reads within the winning chunk
        uint32_t acc = above;
        int b = (int)c * chunks + chunks - 1;
        for (;; --b) {
            uint32_t hb = hist[b];
            if (acc + hb >= target) break;
            acc += hb;
        }
        sc2[0] = (uint32_t)b;
        sc2[1] = acc;
    }
    __syncthreads();
    *outBin = sc2[0];
    *outAbove = sc2[1];
}

// Pass 1 (r6-proven structure): 256-row tiles staged via LDS.
// Phase A: 21 coalesced 256-wide float4 loads -> per-float4 max -> pm[] (box lanes masked).
// Phase B: thread t reduces pm[21t+1 .. 21t+20] (2 lanes/bank = free), writes sortable key.
// NEW: per-row also updates the global 21-bit histogram gH21[u>>11] (replaces the
// former dedicated hist2f scan kernel). LDS 10-bit hist -> gH1 at block end.
__global__ __launch_bounds__(256) void k_score_hist(const float* __restrict__ pred,
                                                    uint32_t* __restrict__ scores,
                                                    uint32_t* __restrict__ gH1,
                                                    uint32_t* __restrict__ gH21,
                                                    float* __restrict__ out, int n) {
    __shared__ float pm[F4PT];
    __shared__ uint32_t h[1024];
    int tid = threadIdx.x;
    if (blockIdx.x == 0 && tid == 0) *out = 0.f;  // out first used 2 dispatches later
    for (int i = tid; i < 1024; i += 256) h[i] = 0;
    uint32_t tid21 = (uint32_t)tid % 21u;
    const float4* pf4 = (const float4*)pred;
    size_t total_f4 = (size_t)n * F4PR;
    int ntiles = (n + RPB - 1) / RPB;
    for (int tile = blockIdx.x; tile < ntiles; tile += gridDim.x) {
        __syncthreads();  // pm reuse guard (also covers h init on first tile)
        size_t gbase = (size_t)tile * F4PT;
        int row0 = tile * RPB;
        if (row0 + RPB <= n) {
#pragma unroll
            for (int it = 0; it < F4PR; ++it) {
                const uint32_t BP = (21u - (4u * (uint32_t)it) % 21u) % 21u;  // box lane
                float4 v = pf4[gbase + it * 256 + tid];
                float m = fmaxf(fmaxf(v.x, v.y), fmaxf(v.z, v.w));
                pm[it * 256 + tid] = (tid21 == BP) ? -INFINITY : m;
            }
        } else {
#pragma unroll
            for (int it = 0; it < F4PR; ++it) {
                const uint32_t BP = (21u - (4u * (uint32_t)it) % 21u) % 21u;
                int l = it * 256 + tid;
                size_t g = gbase + l;
                float m = -INFINITY;
                if (g < total_f4 && tid21 != BP) {
                    float4 v = pf4[g];
                    m = fmaxf(fmaxf(v.x, v.y), fmaxf(v.z, v.w));
                }
                pm[l] = m;
            }
        }
        __syncthreads();
        int row = row0 + tid;
        if (row < n) {
            const float* q = pm + tid * F4PR;
            float m = q[1];
#pragma unroll
            for (int j = 2; j <= 20; ++j) m = fmaxf(m, q[j]);
            uint32_t u = map_f(m);
            scores[row] = u;
            atomicAdd(&h[u >> 22], 1u);
            atomicAdd(&gH21[u >> 11], 1u);  // 21-bit global histogram
        }
    }
    __syncthreads();
    for (int i = tid; i < 1024; i += 256)
        if (h[i]) atomicAdd(&gH1[i], h[i]);
}

// Pass 2: every block computes find1(gH1[1024]) then find2 on the 2048-wide gH21 slice
// -> exact 21-bit threshold bucket t21 (no intermediate scan kernel needed).
// Single scores scan: sum definitely-selected rows; compact bucket-resident candidates.
// Block 0 persists t21 / mprime for the final refinement kernel.
__global__ void k_select2(const float* __restrict__ pred, const uint32_t* __restrict__ scores,
                          const uint32_t* __restrict__ gH1, const uint32_t* __restrict__ gH21,
                          uint32_t* __restrict__ sres, uint32_t* __restrict__ candCnt,
                          unsigned long long* __restrict__ candBuf,
                          float* __restrict__ out, int n, uint32_t K) {
    __shared__ uint32_t s[256];
    __shared__ uint32_t sc2[2];
    __shared__ float wsum[4];
    int tid = threadIdx.x;
    uint32_t bin1, chi1;
    find_parallel(gH1, 1024, K, s, sc2, &bin1, &chi1);
    uint32_t bin2, chi2;
    find_parallel(gH21 + ((size_t)bin1 << 11), 2048, K - chi1, s, sc2, &bin2, &chi2);
    uint32_t t21 = (bin1 << 11) | bin2;
    uint32_t chiTot = chi1 + chi2;        // # keys with (u>>11) > t21
    uint32_t mprime = K - chiTot;         // >= 1, rank within the bucket
    if (blockIdx.x == 0 && tid == 0) { sres[2] = t21; sres[4] = mprime; }
    const uint32_t u_conf = 0xBE800000u;  // map_f(0.25f); low 11 bits zero
    const uint32_t CONF21 = u_conf >> 11;
    bool tcut = (t21 >= CONF21);          // <=> k-th value >= CONF
    float lsum = 0.f;
    int gid = blockIdx.x * 256 + tid;
    int stride = gridDim.x * 256;
    const uint4* s4 = (const uint4*)scores;
    int n4 = n >> 2;
    for (int i = gid; i < n4; i += stride) {
        uint4 uu = s4[i];
#pragma unroll
        for (int j = 0; j < 4; ++j) {
            uint32_t u = (j == 0) ? uu.x : (j == 1) ? uu.y : (j == 2) ? uu.z : uu.w;
            int r = i * 4 + j;
            bool sel = tcut ? ((u >> 11) > t21) : (u >= u_conf);
            if (sel) {
                float4 b = *(const float4*)(pred + (size_t)r * ROWLEN);
                lsum += unmap_f(u) + b.x + b.y + b.z + b.w;
            }
            if (tcut && (u >> 11) == t21) {
                uint32_t pos = atomicAdd(candCnt, 1u);
                if (pos < CANDCAP)
                    candBuf[pos] = ((unsigned long long)u << 32) | (uint32_t)r;
            }
        }
    }
    for (int r = n4 * 4 + gid; r < n; r += stride) {
        uint32_t u = scores[r];
        bool sel = tcut ? ((u >> 11) > t21) : (u >= u_conf);
        if (sel) {
            float4 b = *(const float4*)(pred + (size_t)r * ROWLEN);
            lsum += unmap_f(u) + b.x + b.y + b.z + b.w;
        }
        if (tcut && (u >> 11) == t21) {
            uint32_t pos = atomicAdd(candCnt, 1u);
            if (pos < CANDCAP)
                candBuf[pos] = ((unsigned long long)u << 32) | (uint32_t)r;
        }
    }
    for (int off = 32; off; off >>= 1) lsum += __shfl_down(lsum, off);
    int wid = tid >> 6, lane = tid & 63;
    if (lane == 0) wsum[wid] = lsum;
    __syncthreads();
    if (tid == 0) atomicAdd(out, wsum[0] + wsum[1] + wsum[2] + wsum[3]);
}

// Pass 3 (1 block): refine within the threshold bucket (~1-2K candidates):
// 11-bit LDS histogram -> bin3 -> exact t_u; sum candidates above; tie-break by lowest index.
__global__ void k_final(const float* __restrict__ pred, const uint32_t* __restrict__ sres,
                        const uint32_t* __restrict__ candCnt,
                        const unsigned long long* __restrict__ candBuf,
                        float* __restrict__ out) {
    __shared__ uint32_t h[2048];
    __shared__ uint32_t s[256];
    __shared__ uint32_t sc2[2];
    __shared__ float wsum[4];
    __shared__ uint32_t tb[1024];
    __shared__ uint32_t tc;
    uint32_t t21 = sres[2];
    const uint32_t u_conf = 0xBE800000u;
    const uint32_t CONF21 = u_conf >> 11;
    if (t21 < CONF21) return;  // selection was pure >=CONF; fully handled in k_select2
    uint32_t mprime = sres[4];
    uint32_t cc = *candCnt;
    if (cc > CANDCAP) cc = CANDCAP;
    int tid = threadIdx.x;
    for (int i = tid; i < 2048; i += 256) h[i] = 0;
    if (tid == 0) tc = 0;
    __syncthreads();
    for (uint32_t i = tid; i < cc; i += 256)
        atomicAdd(&h[(uint32_t)(candBuf[i] >> 32) & 0x7FFu], 1u);
    __syncthreads();
    uint32_t bin3, chi3;
    find_parallel(h, 2048, mprime, s, sc2, &bin3, &chi3);
    uint32_t t_u = (t21 << 11) | bin3;
    uint32_t mt = mprime - chi3;  // ties to include (>= 1)
    float fsum = 0.f;
    for (uint32_t i = tid; i < cc; i += 256) {
        unsigned long long v = candBuf[i];
        uint32_t key = (uint32_t)(v >> 32);
        uint32_t r = (uint32_t)v;
        uint32_t low = key & 0x7FFu;
        if (low > bin3) {
            float4 b = *(const float4*)(pred + (size_t)r * ROWLEN);
            fsum += unmap_f(key) + b.x + b.y + b.z + b.w;
        } else if (low == bin3) {
            uint32_t p = atomicAdd(&tc, 1u);
            if (p < 1024) tb[p] = r;
        }
    }
    __syncthreads();
    uint32_t tcnt = tc;
    if (tcnt > 1024) tcnt = 1024;
    if (mt >= tcnt) {
        for (uint32_t i = tid; i < tcnt; i += 256) {
            float4 b = *(const float4*)(pred + (size_t)tb[i] * ROWLEN);
            fsum += b.x + b.y + b.z + b.w;
        }
    } else {
        for (uint32_t i = tid; i < tcnt; i += 256) {
            uint32_t ri = tb[i];
            uint32_t rank = 0;
            for (uint32_t j = 0; j < tcnt; ++j) rank += (tb[j] < ri) ? 1u : 0u;
            if (rank < mt) {
                float4 b = *(const float4*)(pred + (size_t)ri * ROWLEN);
                fsum += b.x + b.y + b.z + b.w;
            }
        }
    }
    for (int off = 32; off; off >>= 1) fsum += __shfl_down(fsum, off);
    int wid = tid >> 6, lane = tid & 63;
    if (lane == 0) wsum[wid] = fsum;
    __syncthreads();
    if (tid == 0)
        atomicAdd(out, wsum[0] + wsum[1] + wsum[2] + wsum[3] + (float)mt * unmap_f(t_u));
}

extern "C" void kernel_launch(void* const* d_in, const int* in_sizes, int n_in,
                              void* d_out, int out_size, void* d_ws, size_t ws_size,
                              hipStream_t stream) {
    const float* pred = (const float*)d_in[0];
    int n = in_sizes[0] / ROWLEN;
    double kd = ceil((double)n * 0.1);
    long kk = (long)kd;
    if (kk < 1) kk = 1;
    if (kk > n) kk = n;
    uint32_t K = (uint32_t)kk;

    uint32_t* ws32 = (uint32_t*)d_ws;
    uint32_t* scores = ws32;          // n words
    uint32_t* gH1 = ws32 + n;         // 1024
    uint32_t* candCnt = gH1 + 1024;   // 16 (1 used)
    uint32_t* sres = candCnt + 16;    // 16
    uint32_t* gH21 = sres + 16;       // 1<<21 words (8 MB), 21-bit histogram
    unsigned long long* candBuf = (unsigned long long*)(gH21 + (1u << 21));  // CANDCAP * 8 B
    float* out = (float*)d_out;

    // One memset covers gH1 | candCnt | sres | gH21 (contiguous, ~8.4 MB).
    hipMemsetAsync(gH1, 0, (1024 + 16 + 16 + (1u << 21)) * sizeof(uint32_t), stream);

    k_score_hist<<<2048, 256, 0, stream>>>(pred, scores, gH1, gH21, out, n);
    k_select2<<<2048, 256, 0, stream>>>(pred, scores, gH1, gH21, sres, candCnt, candBuf,
                                        out, n, K);
    k_final<<<1, 256, 0, stream>>>(pred, sres, candCnt, candBuf, out);
}

// Round 10
// 195.428 us; speedup vs baseline: 1.6082x; 1.6082x over previous
//
#include <hip/hip_runtime.h>
#include <stdint.h>
#include <math.h>

#define ROWLEN 84
#define F4PR 21              // float4s per row (84 floats)
#define RPB 256              // rows per tile (r6-proven)
#define F4PT (RPB * F4PR)    // 5376 float4s per tile
#define CANDCAP (1u << 21)   // >= n, compaction can never overflow

__device__ __forceinline__ uint32_t map_f(float f) {
    uint32_t u = __float_as_uint(f);
    return (u & 0x80000000u) ? ~u : (u | 0x80000000u);
}
__device__ __forceinline__ float unmap_f(uint32_t u) {
    uint32_t b = (u & 0x80000000u) ? (u & 0x7FFFFFFFu) : ~u;
    return __uint_as_float(b);
}

// Parallel bin find over hist[nbins] (global or LDS): bin b with
// suffix(b+1..) < target <= suffix(b..). 256 threads; identical result to all.
__device__ void find_parallel(const uint32_t* hist, int nbins, uint32_t target,
                              uint32_t* s, uint32_t* sc2, uint32_t* outBin, uint32_t* outAbove) {
    int tid = threadIdx.x;
    int chunks = nbins / 256;
    int base = tid * chunks;
    uint32_t part = 0;
    for (int i = 0; i < chunks; ++i) part += hist[base + i];
    s[tid] = part;
    __syncthreads();
    for (int off = 1; off < 256; off <<= 1) {  // suffix sums
        uint32_t v = (tid + off < 256) ? s[tid + off] : 0u;
        __syncthreads();
        s[tid] += v;
        __syncthreads();
    }
    uint32_t above_next = (tid < 255) ? s[tid + 1] : 0u;
    bool mine = (s[tid] >= target) && (above_next < target);  // exactly one thread
    if (mine) { sc2[0] = (uint32_t)tid; sc2[1] = above_next; }
    __syncthreads();
    uint32_t c = sc2[0], above = sc2[1];
    if (tid == 0) {  // <= chunks serial reads within the winning chunk
        uint32_t acc = above;
        int b = (int)c * chunks + chunks - 1;
        for (;; --b) {
            uint32_t hb = hist[b];
            if (acc + hb >= target) break;
            acc += hb;
        }
        sc2[0] = (uint32_t)b;
        sc2[1] = acc;
    }
    __syncthreads();
    *outBin = sc2[0];
    *outAbove = sc2[1];
}

// Pass 1 (r6-proven, verbatim structure): 256-row tiles staged via LDS.
// Phase A: 21 coalesced 256-wide float4 loads -> per-float4 max -> pm[] (box lanes -INF).
// Phase B: thread t reduces pm[21t+1 .. 21t+20] (stride-21 = 2 lanes/bank, free),
//          writes sortable key, 1024-bin LDS hist of top 10 bits -> gH1.
// Also zeroes *out and *candCnt (first used >=2 dispatches later; boundary-fenced).
__global__ __launch_bounds__(256) void k_score_hist(const float* __restrict__ pred,
                                                    uint32_t* __restrict__ scores,
                                                    uint32_t* __restrict__ gH1,
                                                    uint32_t* __restrict__ candCnt,
                                                    float* __restrict__ out, int n) {
    __shared__ float pm[F4PT];
    __shared__ uint32_t h[1024];
    int tid = threadIdx.x;
    if (blockIdx.x == 0 && tid == 0) { *out = 0.f; *candCnt = 0u; }
    for (int i = tid; i < 1024; i += 256) h[i] = 0;
    uint32_t tid21 = (uint32_t)tid % 21u;
    const float4* pf4 = (const float4*)pred;
    size_t total_f4 = (size_t)n * F4PR;
    int ntiles = (n + RPB - 1) / RPB;
    for (int tile = blockIdx.x; tile < ntiles; tile += gridDim.x) {
        __syncthreads();  // pm reuse guard (also covers h init on first tile)
        size_t gbase = (size_t)tile * F4PT;
        int row0 = tile * RPB;
        if (row0 + RPB <= n) {
#pragma unroll
            for (int it = 0; it < F4PR; ++it) {
                const uint32_t BP = (21u - (4u * (uint32_t)it) % 21u) % 21u;  // box lane
                float4 v = pf4[gbase + it * 256 + tid];
                float m = fmaxf(fmaxf(v.x, v.y), fmaxf(v.z, v.w));
                pm[it * 256 + tid] = (tid21 == BP) ? -INFINITY : m;
            }
        } else {
#pragma unroll
            for (int it = 0; it < F4PR; ++it) {
                const uint32_t BP = (21u - (4u * (uint32_t)it) % 21u) % 21u;
                int l = it * 256 + tid;
                size_t g = gbase + l;
                float m = -INFINITY;
                if (g < total_f4 && tid21 != BP) {
                    float4 v = pf4[g];
                    m = fmaxf(fmaxf(v.x, v.y), fmaxf(v.z, v.w));
                }
                pm[l] = m;
            }
        }
        __syncthreads();
        int row = row0 + tid;
        if (row < n) {
            const float* q = pm + tid * F4PR;
            float m = q[1];
#pragma unroll
            for (int j = 2; j <= 20; ++j) m = fmaxf(m, q[j]);
            uint32_t u = map_f(m);
            scores[row] = u;
            atomicAdd(&h[u >> 22], 1u);
        }
    }
    __syncthreads();
    for (int i = tid; i < 1024; i += 256)
        if (h[i]) atomicAdd(&gH1[i], h[i]);
}

// Pass 2 (r7-proven): every block computes find1(gH1); block 0 persists bin1/chi1.
// Level-2 histogram (bits [21:11]) of keys whose top 10 bits == bin1. uint4 scan.
__global__ void k_hist2f(const uint32_t* __restrict__ scores, const uint32_t* __restrict__ gH1,
                         uint32_t* __restrict__ gH2, uint32_t* __restrict__ sres,
                         int n, uint32_t K) {
    __shared__ uint32_t h[2048];
    __shared__ uint32_t s[256];
    __shared__ uint32_t sc2[2];
    for (int i = threadIdx.x; i < 2048; i += 256) h[i] = 0;
    uint32_t bin1, chi1;
    find_parallel(gH1, 1024, K, s, sc2, &bin1, &chi1);
    if (blockIdx.x == 0 && threadIdx.x == 0) { sres[0] = bin1; sres[1] = chi1; }
    int gid = blockIdx.x * 256 + threadIdx.x;
    int stride = gridDim.x * 256;
    const uint4* s4 = (const uint4*)scores;
    int n4 = n >> 2;
    for (int i = gid; i < n4; i += stride) {
        uint4 uu = s4[i];
        if ((uu.x >> 22) == bin1) atomicAdd(&h[(uu.x >> 11) & 0x7FFu], 1u);
        if ((uu.y >> 22) == bin1) atomicAdd(&h[(uu.y >> 11) & 0x7FFu], 1u);
        if ((uu.z >> 22) == bin1) atomicAdd(&h[(uu.z >> 11) & 0x7FFu], 1u);
        if ((uu.w >> 22) == bin1) atomicAdd(&h[(uu.w >> 11) & 0x7FFu], 1u);
    }
    for (int r = n4 * 4 + gid; r < n; r += stride) {
        uint32_t u = scores[r];
        if ((u >> 22) == bin1) atomicAdd(&h[(u >> 11) & 0x7FFu], 1u);
    }
    __syncthreads();
    for (int i = threadIdx.x; i < 2048; i += 256)
        if (h[i]) atomicAdd(&gH2[i], h[i]);
}

// Pass 3 (r7-proven): find2(gH2) -> 21-bit threshold bucket t21. Sum definitely-selected
// rows; compact bucket-resident candidates (plain stores; kernel boundary fences them).
// Block 0 persists t21/mprime.
__global__ void k_select2(const float* __restrict__ pred, const uint32_t* __restrict__ scores,
                          const uint32_t* __restrict__ gH2, uint32_t* __restrict__ sres,
                          uint32_t* __restrict__ candCnt, unsigned long long* __restrict__ candBuf,
                          float* __restrict__ out, int n, uint32_t K) {
    __shared__ uint32_t s[256];
    __shared__ uint32_t sc2[2];
    __shared__ float wsum[4];
    int tid = threadIdx.x;
    uint32_t bin1 = sres[0], chi1 = sres[1];
    uint32_t bin2, chi2;
    find_parallel(gH2, 2048, K - chi1, s, sc2, &bin2, &chi2);
    uint32_t t21 = (bin1 << 11) | bin2;
    uint32_t chiTot = chi1 + chi2;        // # keys with (u>>11) > t21
    uint32_t mprime = K - chiTot;         // >= 1, rank within the bucket
    if (blockIdx.x == 0 && tid == 0) { sres[2] = t21; sres[4] = mprime; }
    const uint32_t u_conf = 0xBE800000u;  // map_f(0.25f); low 11 bits zero
    const uint32_t CONF21 = u_conf >> 11;
    bool tcut = (t21 >= CONF21);          // <=> k-th value >= CONF
    float lsum = 0.f;
    int gid = blockIdx.x * 256 + tid;
    int stride = gridDim.x * 256;
    const uint4* s4 = (const uint4*)scores;
    int n4 = n >> 2;
    for (int i = gid; i < n4; i += stride) {
        uint4 uu = s4[i];
#pragma unroll
        for (int j = 0; j < 4; ++j) {
            uint32_t u = (j == 0) ? uu.x : (j == 1) ? uu.y : (j == 2) ? uu.z : uu.w;
            int r = i * 4 + j;
            bool sel = tcut ? ((u >> 11) > t21) : (u >= u_conf);
            if (sel) {
                float4 b = *(const float4*)(pred + (size_t)r * ROWLEN);
                lsum += unmap_f(u) + b.x + b.y + b.z + b.w;
            }
            if (tcut && (u >> 11) == t21) {
                uint32_t pos = atomicAdd(candCnt, 1u);
                if (pos < CANDCAP)
                    candBuf[pos] = ((unsigned long long)u << 32) | (uint32_t)r;
            }
        }
    }
    for (int r = n4 * 4 + gid; r < n; r += stride) {
        uint32_t u = scores[r];
        bool sel = tcut ? ((u >> 11) > t21) : (u >= u_conf);
        if (sel) {
            float4 b = *(const float4*)(pred + (size_t)r * ROWLEN);
            lsum += unmap_f(u) + b.x + b.y + b.z + b.w;
        }
        if (tcut && (u >> 11) == t21) {
            uint32_t pos = atomicAdd(candCnt, 1u);
            if (pos < CANDCAP)
                candBuf[pos] = ((unsigned long long)u << 32) | (uint32_t)r;
        }
    }
    for (int off = 32; off; off >>= 1) lsum += __shfl_down(lsum, off);
    int wid = tid >> 6, lane = tid & 63;
    if (lane == 0) wsum[wid] = lsum;
    __syncthreads();
    if (tid == 0) atomicAdd(out, wsum[0] + wsum[1] + wsum[2] + wsum[3]);
}

// Pass 4 (r7-proven, 1 block): refine within the threshold bucket (~hundreds of cands):
// 11-bit LDS histogram -> bin3 -> exact t_u; sum candidates above; tie-break lowest index.
__global__ void k_final(const float* __restrict__ pred, const uint32_t* __restrict__ sres,
                        const uint32_t* __restrict__ candCnt,
                        const unsigned long long* __restrict__ candBuf,
                        float* __restrict__ out) {
    __shared__ uint32_t h[2048];
    __shared__ uint32_t s[256];
    __shared__ uint32_t sc2[2];
    __shared__ float wsum[4];
    __shared__ uint32_t tb[1024];
    __shared__ uint32_t tc;
    uint32_t t21 = sres[2];
    const uint32_t u_conf = 0xBE800000u;
    const uint32_t CONF21 = u_conf >> 11;
    if (t21 < CONF21) return;  // selection was pure >=CONF; handled in k_select2
    uint32_t mprime = sres[4];
    uint32_t cc = *candCnt;
    if (cc > CANDCAP) cc = CANDCAP;
    int tid = threadIdx.x;
    for (int i = tid; i < 2048; i += 256) h[i] = 0;
    if (tid == 0) tc = 0;
    __syncthreads();
    for (uint32_t i = tid; i < cc; i += 256)
        atomicAdd(&h[(uint32_t)(candBuf[i] >> 32) & 0x7FFu], 1u);
    __syncthreads();
    uint32_t bin3, chi3;
    find_parallel(h, 2048, mprime, s, sc2, &bin3, &chi3);
    uint32_t t_u = (t21 << 11) | bin3;
    uint32_t mt = mprime - chi3;  // ties to include (>= 1)
    float fsum = 0.f;
    for (uint32_t i = tid; i < cc; i += 256) {
        unsigned long long v = candBuf[i];
        uint32_t key = (uint32_t)(v >> 32);
        uint32_t r = (uint32_t)v;
        uint32_t low = key & 0x7FFu;
        if (low > bin3) {
            float4 b = *(const float4*)(pred + (size_t)r * ROWLEN);
            fsum += unmap_f(key) + b.x + b.y + b.z + b.w;
        } else if (low == bin3) {
            uint32_t p = atomicAdd(&tc, 1u);
            if (p < 1024) tb[p] = r;
        }
    }
    __syncthreads();
    uint32_t tcnt = tc;
    if (tcnt > 1024) tcnt = 1024;
    if (mt >= tcnt) {
        for (uint32_t i = tid; i < tcnt; i += 256) {
            float4 b = *(const float4*)(pred + (size_t)tb[i] * ROWLEN);
            fsum += b.x + b.y + b.z + b.w;
        }
    } else {
        for (uint32_t i = tid; i < tcnt; i += 256) {
            uint32_t ri = tb[i];
            uint32_t rank = 0;
            for (uint32_t j = 0; j < tcnt; ++j) rank += (tb[j] < ri) ? 1u : 0u;
            if (rank < mt) {
                float4 b = *(const float4*)(pred + (size_t)ri * ROWLEN);
                fsum += b.x + b.y + b.z + b.w;
            }
        }
    }
    for (int off = 32; off; off >>= 1) fsum += __shfl_down(fsum, off);
    int wid = tid >> 6, lane = tid & 63;
    if (lane == 0) wsum[wid] = fsum;
    __syncthreads();
    if (tid == 0)
        atomicAdd(out, wsum[0] + wsum[1] + wsum[2] + wsum[3] + (float)mt * unmap_f(t_u));
}

extern "C" void kernel_launch(void* const* d_in, const int* in_sizes, int n_in,
                              void* d_out, int out_size, void* d_ws, size_t ws_size,
                              hipStream_t stream) {
    const float* pred = (const float*)d_in[0];
    int n = in_sizes[0] / ROWLEN;
    double kd = ceil((double)n * 0.1);
    long kk = (long)kd;
    if (kk < 1) kk = 1;
    if (kk > n) kk = n;
    uint32_t K = (uint32_t)kk;

    uint32_t* ws32 = (uint32_t*)d_ws;
    uint32_t* scores = ws32;         // n words
    uint32_t* gH1 = ws32 + n;        // 1024
    uint32_t* gH2 = gH1 + 1024;      // 2048
    uint32_t* candCnt = gH2 + 2048;  // 16 (1 used)
    uint32_t* sres = candCnt + 16;   // 16
    unsigned long long* candBuf = (unsigned long long*)(sres + 16);  // CANDCAP * 8 B
    float* out = (float*)d_out;

    // One memset covers gH1 | gH2 (contiguous, 12.3 KB). out/candCnt zeroed in pass 1.
    hipMemsetAsync(gH1, 0, (1024 + 2048) * sizeof(uint32_t), stream);

    k_score_hist<<<2048, 256, 0, stream>>>(pred, scores, gH1, candCnt, out, n);
    k_hist2f<<<1024, 256, 0, stream>>>(scores, gH1, gH2, sres, n, K);
    k_select2<<<2048, 256, 0, stream>>>(pred, scores, gH2, sres, candCnt, candBuf, out, n, K);
    k_final<<<1, 256, 0, stream>>>(pred, sres, candCnt, candBuf, out);
}